// Round 1
// baseline (525.207 us; speedup 1.0000x reference)
//
#include <hip/hip_runtime.h>
#include <cstddef>

// Problem shape (fixed): N=50000, K=16, C_IN=128, C2=256, C_OUT=128.
#define C_IN  128
#define C2    256
#define C_OUT 128
#define KNBR  16

#define BM 128
#define BN 128
#define BK 32

// C = op(A @ B), A: MxK, B: KxNc, C: MxNc.
// MODE 0: plain.  MODE 1: BN(relu(z + bias)) with inference BN params.
template<int MODE>
__global__ __launch_bounds__(256)
void gemm_k(const float* __restrict__ A, const float* __restrict__ B,
            const float* __restrict__ bias, const float* __restrict__ gamma,
            const float* __restrict__ beta, const float* __restrict__ mean,
            const float* __restrict__ var,
            float* __restrict__ C, int M, int K, int Nc)
{
    __shared__ float As[BK][BM + 4];   // transposed A tile, k-major
    __shared__ float Bs[BK][BN];
    const int tid = threadIdx.x;
    const int tr = tid >> 4;    // 0..15
    const int tc = tid & 15;    // 0..15
    const int m0 = blockIdx.x * BM;
    const int n0 = blockIdx.y * BN;

    float acc[8][8];
    #pragma unroll
    for (int i = 0; i < 8; i++)
        #pragma unroll
        for (int j = 0; j < 8; j++) acc[i][j] = 0.f;

    for (int k0 = 0; k0 < K; k0 += BK) {
        // stage A (BM x BK) -> As transposed (k-major). 1024 float4 loads.
        #pragma unroll
        for (int i = 0; i < 4; i++) {
            int idx = tid + i * 256;
            int row = idx >> 3;          // 0..127
            int c4  = (idx & 7) << 2;    // 0..28
            int gm = m0 + row;
            float4 v = make_float4(0.f, 0.f, 0.f, 0.f);
            if (gm < M) v = *(const float4*)(A + (size_t)gm * K + k0 + c4);
            As[c4 + 0][row] = v.x;
            As[c4 + 1][row] = v.y;
            As[c4 + 2][row] = v.z;
            As[c4 + 3][row] = v.w;
        }
        // stage B (BK x BN) as-is (already k-major)
        #pragma unroll
        for (int i = 0; i < 4; i++) {
            int idx = tid + i * 256;
            int row = idx >> 5;          // 0..31
            int c4  = (idx & 31) << 2;   // 0..124
            *(float4*)&Bs[row][c4] =
                *(const float4*)(B + (size_t)(k0 + row) * Nc + n0 + c4);
        }
        __syncthreads();
        #pragma unroll
        for (int k = 0; k < BK; k++) {
            float4 a0 = *(const float4*)&As[k][tr * 4];
            float4 a1 = *(const float4*)&As[k][64 + tr * 4];
            float4 b0 = *(const float4*)&Bs[k][tc * 4];
            float4 b1 = *(const float4*)&Bs[k][64 + tc * 4];
            float av[8] = {a0.x, a0.y, a0.z, a0.w, a1.x, a1.y, a1.z, a1.w};
            float bv[8] = {b0.x, b0.y, b0.z, b0.w, b1.x, b1.y, b1.z, b1.w};
            #pragma unroll
            for (int i = 0; i < 8; i++)
                #pragma unroll
                for (int j = 0; j < 8; j++)
                    acc[i][j] = fmaf(av[i], bv[j], acc[i][j]);
        }
        __syncthreads();
    }

    // epilogue + store (rows: ih*64 + tr*4 + i, cols: jh*64 + tc*4 + j)
    #pragma unroll
    for (int ih = 0; ih < 2; ih++) {
        #pragma unroll
        for (int i = 0; i < 4; i++) {
            int gm = m0 + ih * 64 + tr * 4 + i;
            if (gm >= M) continue;
            #pragma unroll
            for (int jh = 0; jh < 2; jh++) {
                int gn = n0 + jh * 64 + tc * 4;
                float tmp[4];
                #pragma unroll
                for (int j = 0; j < 4; j++) {
                    float x = acc[ih * 4 + i][jh * 4 + j];
                    if (MODE == 1) {
                        int ch = gn + j;
                        x += bias[ch];
                        x = fmaxf(x, 0.f);
                        float inv = gamma[ch] * rsqrtf(var[ch] + 1e-5f);
                        x = (x - mean[ch]) * inv + beta[ch];
                    }
                    tmp[j] = x;
                }
                float4 v = make_float4(tmp[0], tmp[1], tmp[2], tmp[3]);
                *(float4*)(C + (size_t)gm * Nc + gn) = v;
            }
        }
    }
}

// Fused: gather y/x_bn rows, softmax over k per channel, pool, then
// out_tile(16 x 128) = feat(16 x 256) @ Wm + bm.
__global__ __launch_bounds__(256)
void pool_k(const float* __restrict__ xbn, const float* __restrict__ yv,
            const int* __restrict__ nidx, const float* __restrict__ Wm,
            const float* __restrict__ bm, float* __restrict__ out, int N)
{
    __shared__ float feat[16][C2];
    __shared__ int rows[16 * KNBR];
    const int tid = threadIdx.x;
    const int n0 = blockIdx.x * 16;

    {
        int n = n0 + (tid >> 4);
        rows[tid] = (n < N) ? nidx[n * KNBR + (tid & 15)] : 0;
    }
    __syncthreads();

    const int c = tid;  // channel 0..255
    for (int r = 0; r < 16; r++) {
        float v[KNBR];
        float mx = -3.0e38f;
        #pragma unroll
        for (int k = 0; k < KNBR; k++) {
            v[k] = yv[(size_t)rows[r * KNBR + k] * C2 + c];
            mx = fmaxf(mx, v[k]);
        }
        float den = 0.f, num = 0.f;
        #pragma unroll
        for (int k = 0; k < KNBR; k++) {
            float e = __expf(v[k] - mx);
            den += e;
            num = fmaf(e, xbn[(size_t)rows[r * KNBR + k] * C2 + c], num);
        }
        feat[r][c] = num / den;
    }
    __syncthreads();

    // out tile GEMM: thread t -> row r = t>>4, cols jg..jg+7
    const int r  = tid >> 4;
    const int jg = (tid & 15) << 3;
    float acc[8] = {0, 0, 0, 0, 0, 0, 0, 0};
    for (int ci = 0; ci < C2; ci++) {
        float f = feat[r][ci];
        float4 w0 = *(const float4*)(Wm + ci * C_OUT + jg);
        float4 w1 = *(const float4*)(Wm + ci * C_OUT + jg + 4);
        acc[0] = fmaf(f, w0.x, acc[0]);
        acc[1] = fmaf(f, w0.y, acc[1]);
        acc[2] = fmaf(f, w0.z, acc[2]);
        acc[3] = fmaf(f, w0.w, acc[3]);
        acc[4] = fmaf(f, w1.x, acc[4]);
        acc[5] = fmaf(f, w1.y, acc[5]);
        acc[6] = fmaf(f, w1.z, acc[6]);
        acc[7] = fmaf(f, w1.w, acc[7]);
    }
    int n = n0 + r;
    if (n < N) {
        float4 o0 = make_float4(acc[0] + bm[jg + 0], acc[1] + bm[jg + 1],
                                acc[2] + bm[jg + 2], acc[3] + bm[jg + 3]);
        float4 o1 = make_float4(acc[4] + bm[jg + 4], acc[5] + bm[jg + 5],
                                acc[6] + bm[jg + 6], acc[7] + bm[jg + 7]);
        *(float4*)(out + (size_t)n * C_OUT + jg) = o0;
        *(float4*)(out + (size_t)n * C_OUT + jg + 4) = o1;
    }
}

extern "C" void kernel_launch(void* const* d_in, const int* in_sizes, int n_in,
                              void* d_out, int out_size, void* d_ws, size_t ws_size,
                              hipStream_t stream)
{
    const float* features = (const float*)d_in[0];
    const int*   nidx     = (const int*)d_in[1];
    const float* W1       = (const float*)d_in[2];
    const float* b1       = (const float*)d_in[3];
    const float* gamma    = (const float*)d_in[4];
    const float* beta     = (const float*)d_in[5];
    const float* mean     = (const float*)d_in[6];
    const float* var      = (const float*)d_in[7];
    const float* Ws       = (const float*)d_in[8];
    const float* Wm       = (const float*)d_in[9];
    const float* bm       = (const float*)d_in[10];
    float* out = (float*)d_out;

    const int N = in_sizes[0] / C_IN;   // 50000

    float* xbn = (float*)d_ws;                       // N x 256
    float* yv  = xbn + (size_t)N * C2;               // N x 256

    // K1: xbn = BN(relu(features @ W1 + b1))
    dim3 g1((N + BM - 1) / BM, C2 / BN);
    gemm_k<1><<<g1, 256, 0, stream>>>(features, W1, b1, gamma, beta, mean, var,
                                      xbn, N, C_IN, C2);
    // K2: yv = xbn @ Ws
    dim3 g2((N + BM - 1) / BM, C2 / BN);
    gemm_k<0><<<g2, 256, 0, stream>>>(xbn, Ws, nullptr, nullptr, nullptr,
                                      nullptr, nullptr, yv, N, C2, C2);
    // K3: gather + softmax-pool + output projection
    pool_k<<<(N + 15) / 16, 256, 0, stream>>>(xbn, yv, nidx, Wm, bm, out, N);
}

// Round 2
// 489.928 us; speedup vs baseline: 1.0720x; 1.0720x over previous
//
#include <hip/hip_runtime.h>
#include <cstddef>

// Problem shape (fixed): N=50000, K=16, C_IN=128, C2=256, C_OUT=128.
#define C_IN  128
#define C2    256
#define C_OUT 128
#define KNBR  16

#define BM 128
#define BN 128
#define BK 32

typedef unsigned short u16;

__device__ __forceinline__ float bf2f(u16 h) {
    return __uint_as_float(((unsigned int)h) << 16);
}
__device__ __forceinline__ u16 f2bf(float x) {
    unsigned int u = __float_as_uint(x);
    return (u16)((u + 0x7fffu + ((u >> 16) & 1u)) >> 16);
}

// C = op(A @ B).  MODE 1: BN(relu(z+bias)) -> fp32 C AND bf16 x-half of packed.
// MODE 0: plain -> bf16 y-half of packed only.
// packed row layout (per point, 512 u16): [y[0..255] bf16][x[0..255] bf16].
template<int MODE>
__global__ __launch_bounds__(256)
void gemm_k(const float* __restrict__ A, const float* __restrict__ B,
            const float* __restrict__ bias, const float* __restrict__ gamma,
            const float* __restrict__ beta, const float* __restrict__ mean,
            const float* __restrict__ var,
            float* __restrict__ C, u16* __restrict__ packed,
            int M, int K, int Nc)
{
    __shared__ float As[BK][BM + 4];   // transposed A tile, k-major
    __shared__ float Bs[BK][BN];
    const int tid = threadIdx.x;
    const int tr = tid >> 4;    // 0..15
    const int tc = tid & 15;    // 0..15
    const int m0 = blockIdx.x * BM;
    const int n0 = blockIdx.y * BN;

    float acc[8][8];
    #pragma unroll
    for (int i = 0; i < 8; i++)
        #pragma unroll
        for (int j = 0; j < 8; j++) acc[i][j] = 0.f;

    for (int k0 = 0; k0 < K; k0 += BK) {
        #pragma unroll
        for (int i = 0; i < 4; i++) {
            int idx = tid + i * 256;
            int row = idx >> 3;          // 0..127
            int c4  = (idx & 7) << 2;    // 0..28
            int gm = m0 + row;
            float4 v = make_float4(0.f, 0.f, 0.f, 0.f);
            if (gm < M) v = *(const float4*)(A + (size_t)gm * K + k0 + c4);
            As[c4 + 0][row] = v.x;
            As[c4 + 1][row] = v.y;
            As[c4 + 2][row] = v.z;
            As[c4 + 3][row] = v.w;
        }
        #pragma unroll
        for (int i = 0; i < 4; i++) {
            int idx = tid + i * 256;
            int row = idx >> 5;          // 0..31
            int c4  = (idx & 31) << 2;   // 0..124
            *(float4*)&Bs[row][c4] =
                *(const float4*)(B + (size_t)(k0 + row) * Nc + n0 + c4);
        }
        __syncthreads();
        #pragma unroll
        for (int k = 0; k < BK; k++) {
            float4 a0 = *(const float4*)&As[k][tr * 4];
            float4 a1 = *(const float4*)&As[k][64 + tr * 4];
            float4 b0 = *(const float4*)&Bs[k][tc * 4];
            float4 b1 = *(const float4*)&Bs[k][64 + tc * 4];
            float av[8] = {a0.x, a0.y, a0.z, a0.w, a1.x, a1.y, a1.z, a1.w};
            float bv[8] = {b0.x, b0.y, b0.z, b0.w, b1.x, b1.y, b1.z, b1.w};
            #pragma unroll
            for (int i = 0; i < 8; i++)
                #pragma unroll
                for (int j = 0; j < 8; j++)
                    acc[i][j] = fmaf(av[i], bv[j], acc[i][j]);
        }
        __syncthreads();
    }

    #pragma unroll
    for (int ih = 0; ih < 2; ih++) {
        #pragma unroll
        for (int i = 0; i < 4; i++) {
            int gm = m0 + ih * 64 + tr * 4 + i;
            if (gm >= M) continue;
            #pragma unroll
            for (int jh = 0; jh < 2; jh++) {
                int gn = n0 + jh * 64 + tc * 4;
                float tmp[4];
                #pragma unroll
                for (int j = 0; j < 4; j++) {
                    float x = acc[ih * 4 + i][jh * 4 + j];
                    if (MODE == 1) {
                        int ch = gn + j;
                        x += bias[ch];
                        x = fmaxf(x, 0.f);
                        float inv = gamma[ch] * rsqrtf(var[ch] + 1e-5f);
                        x = (x - mean[ch]) * inv + beta[ch];
                    }
                    tmp[j] = x;
                }
                ushort4 h;
                h.x = f2bf(tmp[0]); h.y = f2bf(tmp[1]);
                h.z = f2bf(tmp[2]); h.w = f2bf(tmp[3]);
                if (MODE == 1) {
                    *(float4*)(C + (size_t)gm * Nc + gn) =
                        make_float4(tmp[0], tmp[1], tmp[2], tmp[3]);
                    *(ushort4*)(packed + (size_t)gm * 512 + 256 + gn) = h;
                } else {
                    *(ushort4*)(packed + (size_t)gm * 512 + gn) = h;
                }
            }
        }
    }
}

// Gather packed bf16 rows, softmax-pool over k per channel (no max pass --
// |y| is small), then out_tile(16 x 128) = feat(16 x 256) @ Wm + bm.
__global__ __launch_bounds__(256)
void pool_k(const u16* __restrict__ packed, const int* __restrict__ nidx,
            const float* __restrict__ Wm, const float* __restrict__ bm,
            float* __restrict__ out, int N)
{
    __shared__ float feat[16][C2];
    __shared__ int rows[16 * KNBR];
    const int tid = threadIdx.x;
    const int n0 = blockIdx.x * 16;

    {
        int n = n0 + (tid >> 4);
        rows[tid] = (n < N) ? nidx[n * KNBR + (tid & 15)] : 0;
    }
    __syncthreads();

    const int g = tid >> 6;   // point group 0..3 (one wave per point)
    const int l = tid & 63;   // channel quad: channels 4l..4l+3
    #pragma unroll 1
    for (int it = 0; it < 4; it++) {
        const int p = it * 4 + g;
        float d0 = 0.f, d1 = 0.f, d2 = 0.f, d3 = 0.f;
        float u0 = 0.f, u1 = 0.f, u2 = 0.f, u3 = 0.f;
        #pragma unroll
        for (int k = 0; k < KNBR; k++) {
            const size_t base = (size_t)rows[p * KNBR + k] * 512;
            ushort4 yh = *(const ushort4*)(packed + base + l * 4);
            ushort4 xh = *(const ushort4*)(packed + base + 256 + l * 4);
            float e0 = __expf(bf2f(yh.x));
            float e1 = __expf(bf2f(yh.y));
            float e2 = __expf(bf2f(yh.z));
            float e3 = __expf(bf2f(yh.w));
            d0 += e0; d1 += e1; d2 += e2; d3 += e3;
            u0 = fmaf(e0, bf2f(xh.x), u0);
            u1 = fmaf(e1, bf2f(xh.y), u1);
            u2 = fmaf(e2, bf2f(xh.z), u2);
            u3 = fmaf(e3, bf2f(xh.w), u3);
        }
        *(float4*)&feat[p][l * 4] =
            make_float4(u0 / d0, u1 / d1, u2 / d2, u3 / d3);
    }
    __syncthreads();

    // out tile GEMM: thread t -> row r = t>>4, cols jg..jg+7
    const int r  = tid >> 4;
    const int jg = (tid & 15) << 3;
    float acc[8] = {0, 0, 0, 0, 0, 0, 0, 0};
    for (int ci = 0; ci < C2; ci++) {
        float f = feat[r][ci];
        float4 w0 = *(const float4*)(Wm + ci * C_OUT + jg);
        float4 w1 = *(const float4*)(Wm + ci * C_OUT + jg + 4);
        acc[0] = fmaf(f, w0.x, acc[0]);
        acc[1] = fmaf(f, w0.y, acc[1]);
        acc[2] = fmaf(f, w0.z, acc[2]);
        acc[3] = fmaf(f, w0.w, acc[3]);
        acc[4] = fmaf(f, w1.x, acc[4]);
        acc[5] = fmaf(f, w1.y, acc[5]);
        acc[6] = fmaf(f, w1.z, acc[6]);
        acc[7] = fmaf(f, w1.w, acc[7]);
    }
    int n = n0 + r;
    if (n < N) {
        float4 o0 = make_float4(acc[0] + bm[jg + 0], acc[1] + bm[jg + 1],
                                acc[2] + bm[jg + 2], acc[3] + bm[jg + 3]);
        float4 o1 = make_float4(acc[4] + bm[jg + 4], acc[5] + bm[jg + 5],
                                acc[6] + bm[jg + 6], acc[7] + bm[jg + 7]);
        *(float4*)(out + (size_t)n * C_OUT + jg) = o0;
        *(float4*)(out + (size_t)n * C_OUT + jg + 4) = o1;
    }
}

extern "C" void kernel_launch(void* const* d_in, const int* in_sizes, int n_in,
                              void* d_out, int out_size, void* d_ws, size_t ws_size,
                              hipStream_t stream)
{
    const float* features = (const float*)d_in[0];
    const int*   nidx     = (const int*)d_in[1];
    const float* W1       = (const float*)d_in[2];
    const float* b1       = (const float*)d_in[3];
    const float* gamma    = (const float*)d_in[4];
    const float* beta     = (const float*)d_in[5];
    const float* mean     = (const float*)d_in[6];
    const float* var      = (const float*)d_in[7];
    const float* Ws       = (const float*)d_in[8];
    const float* Wm       = (const float*)d_in[9];
    const float* bm       = (const float*)d_in[10];
    float* out = (float*)d_out;

    const int N = in_sizes[0] / C_IN;   // 50000

    float* xbn   = (float*)d_ws;                        // N x 256 fp32
    u16*   packed = (u16*)(xbn + (size_t)N * C2);       // N x 512 bf16

    // K1: xbn = BN(relu(features @ W1 + b1)); also bf16 x-half of packed
    dim3 g1((N + BM - 1) / BM, C2 / BN);
    gemm_k<1><<<g1, 256, 0, stream>>>(features, W1, b1, gamma, beta, mean, var,
                                      xbn, packed, N, C_IN, C2);
    // K2: y = xbn @ Ws -> bf16 y-half of packed
    dim3 g2((N + BM - 1) / BM, C2 / BN);
    gemm_k<0><<<g2, 256, 0, stream>>>(xbn, Ws, nullptr, nullptr, nullptr,
                                      nullptr, nullptr, nullptr, packed,
                                      N, C2, C2);
    // K3: gather + softmax-pool + output projection
    pool_k<<<(N + 15) / 16, 256, 0, stream>>>(packed, nidx, Wm, bm, out, N);
}

// Round 3
// 419.821 us; speedup vs baseline: 1.2510x; 1.1670x over previous
//
#include <hip/hip_runtime.h>
#include <cstddef>

// Problem shape (fixed): N=50000, K=16, C_IN=128, C2=256, C_OUT=128.
#define C_IN  128
#define C2    256
#define C_OUT 128
#define KNBR  16

#define BM 128
#define BN 128
#define BK 32

typedef unsigned short u16;

__device__ __forceinline__ float bf2f(u16 h) {
    return __uint_as_float(((unsigned int)h) << 16);
}
__device__ __forceinline__ u16 f2bf(float x) {
    unsigned int u = __float_as_uint(x);
    return (u16)((u + 0x7fffu + ((u >> 16) & 1u)) >> 16);
}

// C = op(A @ B).
// MODE 1: BN(relu(z+bias)) -> fp32 C AND bf16 x-half of packed.
// MODE 0: plain -> bf16 y-half of packed only.
// MODE 2: z + bias -> fp32 C only (output projection).
// packed row layout (per point, 512 u16): [y[0..255] bf16][x[0..255] bf16].
template<int MODE>
__global__ __launch_bounds__(256)
void gemm_k(const float* __restrict__ A, const float* __restrict__ B,
            const float* __restrict__ bias, const float* __restrict__ gamma,
            const float* __restrict__ beta, const float* __restrict__ mean,
            const float* __restrict__ var,
            float* __restrict__ C, u16* __restrict__ packed,
            int M, int K, int Nc)
{
    __shared__ float As[BK][BM + 4];   // transposed A tile, k-major
    __shared__ float Bs[BK][BN];
    const int tid = threadIdx.x;
    const int tr = tid >> 4;    // 0..15
    const int tc = tid & 15;    // 0..15
    const int m0 = blockIdx.x * BM;
    const int n0 = blockIdx.y * BN;

    float acc[8][8];
    #pragma unroll
    for (int i = 0; i < 8; i++)
        #pragma unroll
        for (int j = 0; j < 8; j++) acc[i][j] = 0.f;

    for (int k0 = 0; k0 < K; k0 += BK) {
        #pragma unroll
        for (int i = 0; i < 4; i++) {
            int idx = tid + i * 256;
            int row = idx >> 3;          // 0..127
            int c4  = (idx & 7) << 2;    // 0..28
            int gm = m0 + row;
            float4 v = make_float4(0.f, 0.f, 0.f, 0.f);
            if (gm < M) v = *(const float4*)(A + (size_t)gm * K + k0 + c4);
            As[c4 + 0][row] = v.x;
            As[c4 + 1][row] = v.y;
            As[c4 + 2][row] = v.z;
            As[c4 + 3][row] = v.w;
        }
        #pragma unroll
        for (int i = 0; i < (BN * BK) / (4 * 256); i++) {
            int idx = tid + i * 256;
            int row = idx / (BN / 4);            // 0..BK-1
            int c4  = (idx % (BN / 4)) << 2;
            *(float4*)&Bs[row][c4] =
                *(const float4*)(B + (size_t)(k0 + row) * Nc + n0 + c4);
        }
        __syncthreads();
        #pragma unroll
        for (int k = 0; k < BK; k++) {
            float4 a0 = *(const float4*)&As[k][tr * 4];
            float4 a1 = *(const float4*)&As[k][64 + tr * 4];
            float4 b0 = *(const float4*)&Bs[k][tc * 4];
            float4 b1 = *(const float4*)&Bs[k][64 + tc * 4];
            float av[8] = {a0.x, a0.y, a0.z, a0.w, a1.x, a1.y, a1.z, a1.w};
            float bv[8] = {b0.x, b0.y, b0.z, b0.w, b1.x, b1.y, b1.z, b1.w};
            #pragma unroll
            for (int i = 0; i < 8; i++)
                #pragma unroll
                for (int j = 0; j < 8; j++)
                    acc[i][j] = fmaf(av[i], bv[j], acc[i][j]);
        }
        __syncthreads();
    }

    #pragma unroll
    for (int ih = 0; ih < 2; ih++) {
        #pragma unroll
        for (int i = 0; i < 4; i++) {
            int gm = m0 + ih * 64 + tr * 4 + i;
            if (gm >= M) continue;
            #pragma unroll
            for (int jh = 0; jh < 2; jh++) {
                int gn = n0 + jh * 64 + tc * 4;
                if (gn >= Nc) continue;
                float tmp[4];
                #pragma unroll
                for (int j = 0; j < 4; j++) {
                    float x = acc[ih * 4 + i][jh * 4 + j];
                    if (MODE == 1) {
                        int ch = gn + j;
                        x += bias[ch];
                        x = fmaxf(x, 0.f);
                        float inv = gamma[ch] * rsqrtf(var[ch] + 1e-5f);
                        x = (x - mean[ch]) * inv + beta[ch];
                    } else if (MODE == 2) {
                        x += bias[gn + j];
                    }
                    tmp[j] = x;
                }
                if (MODE == 1) {
                    *(float4*)(C + (size_t)gm * Nc + gn) =
                        make_float4(tmp[0], tmp[1], tmp[2], tmp[3]);
                    ushort4 h;
                    h.x = f2bf(tmp[0]); h.y = f2bf(tmp[1]);
                    h.z = f2bf(tmp[2]); h.w = f2bf(tmp[3]);
                    *(ushort4*)(packed + (size_t)gm * 512 + 256 + gn) = h;
                } else if (MODE == 0) {
                    ushort4 h;
                    h.x = f2bf(tmp[0]); h.y = f2bf(tmp[1]);
                    h.z = f2bf(tmp[2]); h.w = f2bf(tmp[3]);
                    *(ushort4*)(packed + (size_t)gm * 512 + gn) = h;
                } else {
                    *(float4*)(C + (size_t)gm * Nc + gn) =
                        make_float4(tmp[0], tmp[1], tmp[2], tmp[3]);
                }
            }
        }
    }
}

// K3a: one wave per point. Gather 16 packed bf16 rows (y+x halves), issue
// ALL loads before consumption (max MLP), softmax-pool over k per channel
// (no max pass -- |y| small), write feat row fp32.
__global__ __launch_bounds__(256)
void gather_k(const u16* __restrict__ packed, const int* __restrict__ nidx,
              float* __restrict__ feat, int N)
{
    __shared__ int rows[4 * KNBR];
    const int tid = threadIdx.x;
    const int p0 = blockIdx.x * 4;

    if (tid < 4 * KNBR) {
        int n = p0 + (tid >> 4);
        rows[tid] = (n < N) ? nidx[n * KNBR + (tid & 15)] : 0;
    }
    __syncthreads();

    const int w = tid >> 6;       // wave id 0..3 -> point p0+w
    const int l = tid & 63;       // channels 4l..4l+3
    const int p = p0 + w;
    if (p >= N) return;

    // issue all 32 loads up front
    ushort4 yh[KNBR], xh[KNBR];
    #pragma unroll
    for (int k = 0; k < KNBR; k++) {
        const size_t base = (size_t)rows[w * KNBR + k] * 512;
        yh[k] = *(const ushort4*)(packed + base + l * 4);
        xh[k] = *(const ushort4*)(packed + base + 256 + l * 4);
    }

    float d0 = 0.f, d1 = 0.f, d2 = 0.f, d3 = 0.f;
    float u0 = 0.f, u1 = 0.f, u2 = 0.f, u3 = 0.f;
    #pragma unroll
    for (int k = 0; k < KNBR; k++) {
        float e0 = __expf(bf2f(yh[k].x));
        float e1 = __expf(bf2f(yh[k].y));
        float e2 = __expf(bf2f(yh[k].z));
        float e3 = __expf(bf2f(yh[k].w));
        d0 += e0; d1 += e1; d2 += e2; d3 += e3;
        u0 = fmaf(e0, bf2f(xh[k].x), u0);
        u1 = fmaf(e1, bf2f(xh[k].y), u1);
        u2 = fmaf(e2, bf2f(xh[k].z), u2);
        u3 = fmaf(e3, bf2f(xh[k].w), u3);
    }
    *(float4*)(feat + (size_t)p * C2 + l * 4) =
        make_float4(u0 / d0, u1 / d1, u2 / d2, u3 / d3);
}

extern "C" void kernel_launch(void* const* d_in, const int* in_sizes, int n_in,
                              void* d_out, int out_size, void* d_ws, size_t ws_size,
                              hipStream_t stream)
{
    const float* features = (const float*)d_in[0];
    const int*   nidx     = (const int*)d_in[1];
    const float* W1       = (const float*)d_in[2];
    const float* b1       = (const float*)d_in[3];
    const float* gamma    = (const float*)d_in[4];
    const float* beta     = (const float*)d_in[5];
    const float* mean     = (const float*)d_in[6];
    const float* var      = (const float*)d_in[7];
    const float* Ws       = (const float*)d_in[8];
    const float* Wm       = (const float*)d_in[9];
    const float* bm       = (const float*)d_in[10];
    float* out = (float*)d_out;

    const int N = in_sizes[0] / C_IN;   // 50000

    float* xbn    = (float*)d_ws;                    // N x 256 fp32
    u16*   packed = (u16*)(xbn + (size_t)N * C2);    // N x 512 bf16
    float* feat   = xbn;   // alias: xbn dead after K2, feat written in K3a

    // K1: xbn = BN(relu(features @ W1 + b1)); also bf16 x-half of packed
    dim3 g1((N + BM - 1) / BM, C2 / BN);
    gemm_k<1><<<g1, 256, 0, stream>>>(features, W1, b1, gamma, beta, mean, var,
                                      xbn, packed, N, C_IN, C2);
    // K2: y = xbn @ Ws -> bf16 y-half of packed
    dim3 g2((N + BM - 1) / BM, C2 / BN);
    gemm_k<0><<<g2, 256, 0, stream>>>(xbn, Ws, nullptr, nullptr, nullptr,
                                      nullptr, nullptr, nullptr, packed,
                                      N, C2, C2);
    // K3a: gather + softmax-pool -> feat (aliases xbn)
    gather_k<<<(N + 3) / 4, 256, 0, stream>>>(packed, nidx, feat, N);
    // K3b: out = feat @ Wm + bm
    dim3 g3((N + BM - 1) / BM, 1);
    gemm_k<2><<<g3, 256, 0, stream>>>(feat, Wm, bm, nullptr, nullptr,
                                      nullptr, nullptr, out, nullptr,
                                      N, C2, C_OUT);
}

// Round 4
// 274.171 us; speedup vs baseline: 1.9156x; 1.5312x over previous
//
#include <hip/hip_runtime.h>
#include <cstddef>

// Problem shape (fixed): N=50000, K=16, C_IN=128, C2=256, C_OUT=128.
#define C_IN  128
#define C2    256
#define C_OUT 128
#define KNBR  16

typedef unsigned short u16;
typedef __attribute__((ext_vector_type(8))) short bf16x8;   // 8 bf16 (4 VGPRs)
typedef __attribute__((ext_vector_type(4))) float f32x4;

__device__ __forceinline__ float bf2f(u16 h) {
    return __uint_as_float(((unsigned int)h) << 16);
}
__device__ __forceinline__ u16 f2bf(float x) {
    unsigned int u = __float_as_uint(x);
    return (u16)((u + 0x7fffu + ((u >> 16) & 1u)) >> 16);
}

// Transpose + convert the three weight matrices to bf16, n-major [N][K]:
// W1 [128][256] -> W1t [256][128]; Ws [256][256] -> Wst [256][256];
// Wm [256][128] -> Wmt [128][256].
__global__ void prep_k(const float* __restrict__ W1, const float* __restrict__ Ws,
                       const float* __restrict__ Wm, u16* __restrict__ W1t,
                       u16* __restrict__ Wst, u16* __restrict__ Wmt)
{
    const int n = blockIdx.x, t = threadIdx.x;
    if (blockIdx.y == 0) {
        if (t < 128) W1t[n * 128 + t] = f2bf(W1[t * 256 + n]);
    } else if (blockIdx.y == 1) {
        Wst[n * 256 + t] = f2bf(Ws[t * 256 + n]);
    } else {
        if (n < 128) Wmt[n * 256 + t] = f2bf(Wm[t * 128 + n]);
    }
}

// MFMA bf16 GEMM, 128x128 tile, 4 waves, 4x4 16x16x32 frags per wave.
// A: row-major, either fp32 (convert on stage) or bf16 with stride lda,
// offset aoff (elements). Bt: n-major bf16 [Nc][Kd].
// MODE 1: BN(relu(z+bias)) -> bf16 x-half of packed.
// MODE 0: plain -> bf16 y-half of packed.
// MODE 2: z + bias -> fp32 Cf.
template<int MODE, bool A_BF16>
__global__ __launch_bounds__(256)
void mfma_gemm(const void* __restrict__ Ap, int lda, int aoff,
               const u16* __restrict__ Bt,
               const float* __restrict__ bias, const float* __restrict__ gamma,
               const float* __restrict__ beta, const float* __restrict__ mean,
               const float* __restrict__ var,
               float* __restrict__ Cf, u16* __restrict__ packed,
               int M, int Kd, int Nc)
{
    __shared__ u16 As[128][40];   // +8 pad: 2-way bank alias (free)
    __shared__ u16 Bs[128][40];
    const int tid = threadIdx.x;
    const int w = tid >> 6, l = tid & 63, q = l >> 4, r = l & 15;
    const int wm = w & 1, wn = w >> 1;
    const int m0 = blockIdx.x * 128, n0 = blockIdx.y * 128;

    f32x4 acc[4][4] = {};

    for (int k0 = 0; k0 < Kd; k0 += 32) {
        if (A_BF16) {
            const u16* A = (const u16*)Ap;
            #pragma unroll
            for (int i = 0; i < 2; i++) {
                int idx = tid + i * 256;
                int row = idx >> 2, g = (idx & 3) * 8;
                int gm = m0 + row;
                uint4 v = make_uint4(0u, 0u, 0u, 0u);
                if (gm < M)
                    v = *(const uint4*)(A + (size_t)gm * lda + aoff + k0 + g);
                *(uint4*)&As[row][g] = v;
            }
        } else {
            const float* A = (const float*)Ap;
            #pragma unroll
            for (int i = 0; i < 4; i++) {
                int idx = tid + i * 256;
                int row = idx >> 3, g = (idx & 7) * 4;
                int gm = m0 + row;
                float4 v = make_float4(0.f, 0.f, 0.f, 0.f);
                if (gm < M)
                    v = *(const float4*)(A + (size_t)gm * lda + k0 + g);
                ushort4 h;
                h.x = f2bf(v.x); h.y = f2bf(v.y);
                h.z = f2bf(v.z); h.w = f2bf(v.w);
                *(ushort4*)&As[row][g] = h;
            }
        }
        #pragma unroll
        for (int i = 0; i < 2; i++) {
            int idx = tid + i * 256;
            int row = idx >> 2, g = (idx & 3) * 8;
            *(uint4*)&Bs[row][g] =
                *(const uint4*)(Bt + (size_t)(n0 + row) * Kd + k0 + g);
        }
        __syncthreads();

        bf16x8 af[4], bfr[4];
        #pragma unroll
        for (int i = 0; i < 4; i++)
            af[i] = *(const bf16x8*)&As[wm * 64 + i * 16 + r][q * 8];
        #pragma unroll
        for (int j = 0; j < 4; j++)
            bfr[j] = *(const bf16x8*)&Bs[wn * 64 + j * 16 + r][q * 8];
        #pragma unroll
        for (int i = 0; i < 4; i++)
            #pragma unroll
            for (int j = 0; j < 4; j++)
                acc[i][j] = __builtin_amdgcn_mfma_f32_16x16x32_bf16(
                    af[i], bfr[j], acc[i][j], 0, 0, 0);
        __syncthreads();
    }

    // epilogue: lane (q,r), reg p -> row m0+wm*64+i*16+q*4+p, col n0+wn*64+j*16+r
    #pragma unroll
    for (int j = 0; j < 4; j++) {
        const int ch = n0 + wn * 64 + j * 16 + r;
        float bi = 0.f, be = 0.f, mu = 0.f, iv = 0.f, bo = 0.f;
        if (MODE == 1) {
            bi = bias[ch]; be = beta[ch]; mu = mean[ch];
            iv = gamma[ch] * rsqrtf(var[ch] + 1e-5f);
        }
        if (MODE == 2) bo = bias[ch];
        #pragma unroll
        for (int i = 0; i < 4; i++) {
            const int mb = m0 + wm * 64 + i * 16 + q * 4;
            #pragma unroll
            for (int p = 0; p < 4; p++) {
                const int m = mb + p;
                if (m >= M) continue;
                float x = acc[i][j][p];
                if (MODE == 1) {
                    x = fmaxf(x + bi, 0.f);
                    x = (x - mu) * iv + be;
                    packed[(size_t)m * 512 + 256 + ch] = f2bf(x);
                } else if (MODE == 0) {
                    packed[(size_t)m * 512 + ch] = f2bf(x);
                } else {
                    Cf[(size_t)m * Nc + ch] = x + bo;
                }
            }
        }
    }
}

// One wave per point: gather 16 packed bf16 rows (y+x halves), all loads
// issued up front, softmax-pool over k per channel (no max pass -- |y| is
// small), write feat row bf16.
__global__ __launch_bounds__(256)
void gather_k(const u16* __restrict__ packed, const int* __restrict__ nidx,
              u16* __restrict__ featb, int N)
{
    __shared__ int rows[4 * KNBR];
    const int tid = threadIdx.x;
    const int p0 = blockIdx.x * 4;

    if (tid < 4 * KNBR) {
        int n = p0 + (tid >> 4);
        rows[tid] = (n < N) ? nidx[n * KNBR + (tid & 15)] : 0;
    }
    __syncthreads();

    const int w = tid >> 6;       // wave id 0..3 -> point p0+w
    const int l = tid & 63;       // channels 4l..4l+3
    const int p = p0 + w;
    if (p >= N) return;

    ushort4 yh[KNBR], xh[KNBR];
    #pragma unroll
    for (int k = 0; k < KNBR; k++) {
        const size_t base = (size_t)rows[w * KNBR + k] * 512;
        yh[k] = *(const ushort4*)(packed + base + l * 4);
        xh[k] = *(const ushort4*)(packed + base + 256 + l * 4);
    }

    float d0 = 0.f, d1 = 0.f, d2 = 0.f, d3 = 0.f;
    float u0 = 0.f, u1 = 0.f, u2 = 0.f, u3 = 0.f;
    #pragma unroll
    for (int k = 0; k < KNBR; k++) {
        float e0 = __expf(bf2f(yh[k].x));
        float e1 = __expf(bf2f(yh[k].y));
        float e2 = __expf(bf2f(yh[k].z));
        float e3 = __expf(bf2f(yh[k].w));
        d0 += e0; d1 += e1; d2 += e2; d3 += e3;
        u0 = fmaf(e0, bf2f(xh[k].x), u0);
        u1 = fmaf(e1, bf2f(xh[k].y), u1);
        u2 = fmaf(e2, bf2f(xh[k].z), u2);
        u3 = fmaf(e3, bf2f(xh[k].w), u3);
    }
    ushort4 o;
    o.x = f2bf(u0 / d0); o.y = f2bf(u1 / d1);
    o.z = f2bf(u2 / d2); o.w = f2bf(u3 / d3);
    *(ushort4*)(featb + (size_t)p * C2 + l * 4) = o;
}

extern "C" void kernel_launch(void* const* d_in, const int* in_sizes, int n_in,
                              void* d_out, int out_size, void* d_ws, size_t ws_size,
                              hipStream_t stream)
{
    const float* features = (const float*)d_in[0];
    const int*   nidx     = (const int*)d_in[1];
    const float* W1       = (const float*)d_in[2];
    const float* b1       = (const float*)d_in[3];
    const float* gamma    = (const float*)d_in[4];
    const float* beta     = (const float*)d_in[5];
    const float* mean     = (const float*)d_in[6];
    const float* var      = (const float*)d_in[7];
    const float* Ws       = (const float*)d_in[8];
    const float* Wm       = (const float*)d_in[9];
    const float* bm       = (const float*)d_in[10];
    float* out = (float*)d_out;

    const int N = in_sizes[0] / C_IN;   // 50000

    u16* packed = (u16*)d_ws;                      // N x 512 ([y|x] bf16)
    u16* featb  = packed + (size_t)N * 512;        // N x 256 bf16
    u16* W1t    = featb + (size_t)N * 256;         // 256 x 128
    u16* Wst    = W1t + 256 * 128;                 // 256 x 256
    u16* Wmt    = Wst + 256 * 256;                 // 128 x 256

    // P0: weights -> bf16, n-major
    prep_k<<<dim3(256, 3), 256, 0, stream>>>(W1, Ws, Wm, W1t, Wst, Wmt);

    const int MT = (N + 127) / 128;   // 391

    // K1: x = BN(relu(features @ W1 + b1)) -> packed x-half
    mfma_gemm<1, false><<<dim3(MT, 2), 256, 0, stream>>>(
        features, C_IN, 0, W1t, b1, gamma, beta, mean, var,
        nullptr, packed, N, C_IN, C2);
    // K2: y = x @ Ws -> packed y-half (A = packed x-half, bf16)
    mfma_gemm<0, true><<<dim3(MT, 2), 256, 0, stream>>>(
        packed, 512, 256, Wst, nullptr, nullptr, nullptr, nullptr, nullptr,
        nullptr, packed, N, C2, C2);
    // K3a: gather + softmax-pool -> featb
    gather_k<<<(N + 3) / 4, 256, 0, stream>>>(packed, nidx, featb, N);
    // K3b: out = featb @ Wm + bm
    mfma_gemm<2, true><<<dim3(MT, 1), 256, 0, stream>>>(
        featb, C2, 0, Wmt, bm, nullptr, nullptr, nullptr, nullptr,
        out, nullptr, N, C2, C_OUT);
}